// Round 5
// baseline (224.395 us; speedup 1.0000x reference)
//
#include <hip/hip_runtime.h>

#define L_LEN 8192
#define N_FFT 16384   // 2*L
#define NB    1024    // threads per block; each thread owns 16 points per pass

// LDS (128 KiB) caps occupancy at 1 block/CU = 16 waves = 4 waves/EU.
// Pin the allocator to exactly 4 waves/EU so it uses the full 128-VGPR
// budget instead of spilling to chase an unreachable 8 waves/EU.
#define LB __launch_bounds__(NB) __attribute__((amdgpu_waves_per_eu(4, 4)))

// bijective LDS index swizzle: spreads bank-row slot (i%16 for float2)
// with all higher index bits, killing stride-conflicts in every phase.
__device__ __forceinline__ int swz(int i) {
    return i ^ ((((i) >> 4) ^ ((i) >> 8) ^ ((i) >> 12)) & 15);
}

// reverse 6 base-4 digits (12-bit index) — quad index <-> low 6 digits of bin
__device__ __forceinline__ int rev4_12(int m) {
    int r = 0;
#pragma unroll
    for (int d = 0; d < 6; ++d) { r = (r << 2) | (m & 3); m >>= 2; }
    return r;
}

__device__ __forceinline__ float2 cmul(float2 a, float cr, float ci) {
    return make_float2(a.x * cr - a.y * ci, a.x * ci + a.y * cr);
}

// DIF radix-4 butterfly with twiddle W = (c,s) (negative-angle convention).
__device__ __forceinline__ void bfly_dif_w(float2& x0, float2& x1, float2& x2, float2& x3,
                                           float c, float s) {
    float Ar = x0.x + x2.x, Ai = x0.y + x2.y;
    float Br = x0.x - x2.x, Bi = x0.y - x2.y;
    float Cr = x1.x + x3.x, Ci = x1.y + x3.y;
    float Dr = x1.x - x3.x, Di = x1.y - x3.y;
    float w2r = c * c - s * s, w2i = 2.f * c * s;
    float w3r = w2r * c - w2i * s, w3i = w2r * s + w2i * c;
    x0 = make_float2(Ar + Cr, Ai + Ci);
    x1 = cmul(make_float2(Br + Di, Bi - Dr), c, s);
    x2 = cmul(make_float2(Ar - Cr, Ai - Ci), w2r, w2i);
    x3 = cmul(make_float2(Br - Di, Bi + Dr), w3r, w3i);
}

// DIT radix-4 butterfly: twiddle-multiply inputs then combine.
__device__ __forceinline__ void bfly_dit_w(float2& x0, float2& x1, float2& x2, float2& x3,
                                           float c, float s) {
    float w2r = c * c - s * s, w2i = 2.f * c * s;
    float w3r = w2r * c - w2i * s, w3i = w2r * s + w2i * c;
    float2 a1 = cmul(x1, c, s);
    float2 a2 = cmul(x2, w2r, w2i);
    float2 a3 = cmul(x3, w3r, w3i);
    float Er = x0.x + a2.x, Ei = x0.y + a2.y;
    float Fr = x0.x - a2.x, Fi = x0.y - a2.y;
    float Gr = a1.x + a3.x, Gi = a1.y + a3.y;
    float Kr = a1.x - a3.x, Ki = a1.y - a3.y;
    x0 = make_float2(Er + Gr, Ei + Gi);
    x1 = make_float2(Fr - Ki, Fi + Kr);
    x2 = make_float2(Er - Gr, Ei - Gi);
    x3 = make_float2(Fr + Ki, Fi - Kr);
}

// twiddle-free DIF (t=0)
__device__ __forceinline__ void bfly_dif_1(float2* z) {
    float Ar = z[0].x + z[2].x, Ai = z[0].y + z[2].y;
    float Br = z[0].x - z[2].x, Bi = z[0].y - z[2].y;
    float Cr = z[1].x + z[3].x, Ci = z[1].y + z[3].y;
    float Dr = z[1].x - z[3].x, Di = z[1].y - z[3].y;
    z[0] = make_float2(Ar + Cr, Ai + Ci);
    z[1] = make_float2(Br + Di, Bi - Dr);
    z[2] = make_float2(Ar - Cr, Ai - Ci);
    z[3] = make_float2(Br - Di, Bi + Dr);
}

// twiddle-free DIT (t=0)
__device__ __forceinline__ void bfly_dit_1(float2* z) {
    float Er = z[0].x + z[2].x, Ei = z[0].y + z[2].y;
    float Fr = z[0].x - z[2].x, Fi = z[0].y - z[2].y;
    float Gr = z[1].x + z[3].x, Gi = z[1].y + z[3].y;
    float Kr = z[1].x - z[3].x, Ki = z[1].y - z[3].y;
    z[0] = make_float2(Er + Gr, Ei + Gi);
    z[1] = make_float2(Fr - Ki, Fi + Kr);
    z[2] = make_float2(Er - Gr, Ei - Gi);
    z[3] = make_float2(Fr + Ki, Fi - Kr);
}

// pointwise Y = X*H from Z[m], Z[N-m] of the packed z = x + i*h transform
__device__ __forceinline__ void pointwise_pair(float2& Zm, float2& Zr) {
    float Xr = 0.5f * (Zm.x + Zr.x), Xi = 0.5f * (Zm.y - Zr.y);
    float Hr = 0.5f * (Zm.y + Zr.y), Hi = 0.5f * (Zr.x - Zm.x);
    float Yr = Xr * Hr - Xi * Hi;
    float Yi = Xr * Hi + Xi * Hr;
    Zm = make_float2(Yr, Yi);
    Zr = make_float2(Yr, -Yi);
}

// Fused forward DIF pair: stage q=QA then q=QA/4, one LDS round-trip.
template<int QA>
__device__ __forceinline__ void fwd_pair(float2* lds, int tid) {
    constexpr int QB = QA / 4;
    // cos/sin of 2*pi*j/16 — folded to literals under full unroll
    constexpr float C16v[4] = {1.0f, 0.92387953251128674f, 0.70710678118654752f, 0.38268343236508977f};
    constexpr float S16v[4] = {0.0f, 0.38268343236508977f, 0.70710678118654752f, 0.92387953251128674f};
    const int g = tid / QB;
    const int u = tid % QB;
    const int base = g * (4 * QA) + u;
    float2 r[4][4];
#pragma unroll
    for (int jA = 0; jA < 4; ++jA)
#pragma unroll
        for (int jB = 0; jB < 4; ++jB)
            r[jA][jB] = lds[swz(base + jA * QA + jB * QB)];

    // Stage A twiddle for column jB is W^(u + jB*QB) = W^u * e^{-2pi*i*jB/16}
    const float angA = -6.283185307179586f / (float)(4 * QA);
    float snU, csU;
    __sincosf(angA * (float)u, &snU, &csU);
#pragma unroll
    for (int jB = 0; jB < 4; ++jB) {
        float c = csU * C16v[jB] + snU * S16v[jB];
        float s = snU * C16v[jB] - csU * S16v[jB];
        bfly_dif_w(r[0][jB], r[1][jB], r[2][jB], r[3][jB], c, s);
    }
    const float angB = -6.283185307179586f / (float)(4 * QB);
    float snB, csB;
    __sincosf(angB * (float)u, &snB, &csB);
#pragma unroll
    for (int jA = 0; jA < 4; ++jA)
        bfly_dif_w(r[jA][0], r[jA][1], r[jA][2], r[jA][3], csB, snB);

#pragma unroll
    for (int jA = 0; jA < 4; ++jA)
#pragma unroll
        for (int jB = 0; jB < 4; ++jB)
            lds[swz(base + jA * QA + jB * QB)] = r[jA][jB];
}

// Fused inverse DIT pair: stage q=QA then q=4*QA, one LDS round-trip.
template<int QA>
__device__ __forceinline__ void inv_pair(float2* lds, int tid) {
    constexpr int QB = 4 * QA;
    constexpr float C16v[4] = {1.0f, 0.92387953251128674f, 0.70710678118654752f, 0.38268343236508977f};
    constexpr float S16v[4] = {0.0f, 0.38268343236508977f, 0.70710678118654752f, 0.92387953251128674f};
    const int G = tid / QA;
    const int u = tid % QA;
    const int base = G * (16 * QA) + u;
    float2 r[4][4];
#pragma unroll
    for (int jA = 0; jA < 4; ++jA)
#pragma unroll
        for (int jB = 0; jB < 4; ++jB)
            r[jA][jB] = lds[swz(base + jA * QA + jB * QB)];

    const float angA = 6.283185307179586f / (float)(4 * QA);
    float snA, csA;
    __sincosf(angA * (float)u, &snA, &csA);
#pragma unroll
    for (int jB = 0; jB < 4; ++jB)
        bfly_dit_w(r[0][jB], r[1][jB], r[2][jB], r[3][jB], csA, snA);

    // Stage B twiddle for row jA is W^(u + jA*QA) = W^u * e^{+2pi*i*jA/16}
    const float angB = 6.283185307179586f / (float)(4 * QB);
    float snU, csU;
    __sincosf(angB * (float)u, &snU, &csU);
#pragma unroll
    for (int jA = 0; jA < 4; ++jA) {
        float c = csU * C16v[jA] - snU * S16v[jA];
        float s = snU * C16v[jA] + csU * S16v[jA];
        bfly_dit_w(r[jA][0], r[jA][1], r[jA][2], r[jA][3], c, s);
    }

#pragma unroll
    for (int jA = 0; jA < 4; ++jA)
#pragma unroll
        for (int jB = 0; jB < 4; ++jB)
            lds[swz(base + jA * QA + jB * QB)] = r[jA][jB];
}

__global__ LB
void fftconv_kernel(const float* __restrict__ xin,
                    const float* __restrict__ hin,
                    float* __restrict__ out)
{
    __shared__ float2 lds[N_FFT];   // 128 KiB

    const int row = blockIdx.x;
    const int tid = threadIdx.x;
    const float* xr = xin + (size_t)row * L_LEN;
    const float* hr = hin + (size_t)row * L_LEN;

    // ---- load z = x + i*h, zero-pad to N ----
#pragma unroll
    for (int i = tid; i < L_LEN / 4; i += NB) {
        float4 xv = ((const float4*)xr)[i];
        float4 hv = ((const float4*)hr)[i];
        int j = i * 4;
        lds[swz(j + 0)] = make_float2(xv.x, hv.x);
        lds[swz(j + 1)] = make_float2(xv.y, hv.y);
        lds[swz(j + 2)] = make_float2(xv.z, hv.z);
        lds[swz(j + 3)] = make_float2(xv.w, hv.w);
    }
#pragma unroll
    for (int j = L_LEN + tid; j < N_FFT; j += NB)
        lds[swz(j)] = make_float2(0.f, 0.f);
    __syncthreads();

    // ---- forward: fused radix-16 passes (q = 4096&1024, 256&64, 16&4) ----
    fwd_pair<4096>(lds, tid); __syncthreads();
    fwd_pair<256>(lds, tid);  __syncthreads();
    fwd_pair<16>(lds, tid);   __syncthreads();

    // ---- combo pass: fwd q=1 + Hermitian pointwise + inv q=1, in registers ----
    // Quad at positions 4a..4a+3 (a = rev6(b)) holds bins k*4096 + b.
    // Quad b pairs with quad 4096-b; entry k pairs with partner entry 3-k.
#pragma unroll
    for (int iter = 0; iter < 2; ++iter) {
        const int p = tid + iter * NB;          // p in [0, 2048)
        if (p == 0) {
            // quad a=0 (b=0): bins {0,4096,8192,12288}
            float2 z[4];
#pragma unroll
            for (int k = 0; k < 4; ++k) z[k] = lds[swz(0 + k)];
            bfly_dif_1(z);
            z[0] = make_float2(z[0].x * z[0].y, 0.f);   // bin 0
            z[2] = make_float2(z[2].x * z[2].y, 0.f);   // bin N/2
            pointwise_pair(z[1], z[3]);                 // 4096 <-> 12288
            bfly_dit_1(z);
#pragma unroll
            for (int k = 0; k < 4; ++k) lds[swz(0 + k)] = z[k];
            // quad a=2 (b=2048): bins k*4096+2048; pairs (0,3),(1,2)
            float2 w[4];
#pragma unroll
            for (int k = 0; k < 4; ++k) w[k] = lds[swz(8 + k)];
            bfly_dif_1(w);
            pointwise_pair(w[0], w[3]);
            pointwise_pair(w[1], w[2]);
            bfly_dit_1(w);
#pragma unroll
            for (int k = 0; k < 4; ++k) lds[swz(8 + k)] = w[k];
        } else {
            const int aA = rev4_12(p);
            const int aB = rev4_12(4096 - p);
            float2 A[4], B[4];
#pragma unroll
            for (int k = 0; k < 4; ++k) A[k] = lds[swz(4 * aA + k)];
#pragma unroll
            for (int k = 0; k < 4; ++k) B[k] = lds[swz(4 * aB + k)];
            bfly_dif_1(A);
            bfly_dif_1(B);
            pointwise_pair(A[0], B[3]);
            pointwise_pair(A[1], B[2]);
            pointwise_pair(A[2], B[1]);
            pointwise_pair(A[3], B[0]);
            bfly_dit_1(A);
            bfly_dit_1(B);
#pragma unroll
            for (int k = 0; k < 4; ++k) lds[swz(4 * aA + k)] = A[k];
#pragma unroll
            for (int k = 0; k < 4; ++k) lds[swz(4 * aB + k)] = B[k];
        }
    }
    __syncthreads();

    // ---- inverse: fused radix-16 passes (q = 4&16, 64&256, 1024&4096) ----
    inv_pair<4>(lds, tid);    __syncthreads();
    inv_pair<64>(lds, tid);   __syncthreads();
    inv_pair<1024>(lds, tid); __syncthreads();

    // ---- store first L real parts, scaled by 1/N^2 (net torch-forward 1/n) ----
    const float scale = 1.0f / ((float)N_FFT * (float)N_FFT);   // 2^-28
    float* orow = out + (size_t)row * L_LEN;
#pragma unroll
    for (int i = tid; i < L_LEN / 4; i += NB) {
        int j = 4 * i;
        float4 o;
        o.x = lds[swz(j + 0)].x * scale;
        o.y = lds[swz(j + 1)].x * scale;
        o.z = lds[swz(j + 2)].x * scale;
        o.w = lds[swz(j + 3)].x * scale;
        ((float4*)orow)[i] = o;
    }
}

extern "C" void kernel_launch(void* const* d_in, const int* in_sizes, int n_in,
                              void* d_out, int out_size, void* d_ws, size_t ws_size,
                              hipStream_t stream) {
    const float* x = (const float*)d_in[0];
    const float* h = (const float*)d_in[1];
    float* out = (float*)d_out;
    const int rows = in_sizes[0] / L_LEN;   // 2048
    fftconv_kernel<<<dim3(rows), dim3(NB), 0, stream>>>(x, h, out);
}

// Round 6
// 187.806 us; speedup vs baseline: 1.1948x; 1.1948x over previous
//
#include <hip/hip_runtime.h>

#define L_LEN 8192
#define N_FFT 16384   // 2*L
#define NB    1024    // threads per block; each thread owns 16 points per pass

#define LB __launch_bounds__(NB)

// bijective LDS index swizzle: spreads bank-row slot (i%16 for float2)
// with all higher index bits. GF(2)-LINEAR: swz(a^b) = swz(a)^swz(b).
// Since all our indices decompose as base|off with DISJOINT bit fields,
// swz(base+off) = swz(base) ^ swz(off), and swz(off) constant-folds.
__host__ __device__ constexpr int swz(int i) {
    return i ^ ((((i) >> 4) ^ ((i) >> 8) ^ ((i) >> 12)) & 15);
}

// reverse 6 base-4 digits (12-bit index) — quad index <-> low 6 digits of bin
__device__ __forceinline__ int rev4_12(int m) {
    int r = 0;
#pragma unroll
    for (int d = 0; d < 6; ++d) { r = (r << 2) | (m & 3); m >>= 2; }
    return r;
}

__device__ __forceinline__ float2 cmul(float2 a, float cr, float ci) {
    return make_float2(a.x * cr - a.y * ci, a.x * ci + a.y * cr);
}

// DIF radix-4 butterfly with twiddle W = (c,s) (negative-angle convention).
__device__ __forceinline__ void bfly_dif_w(float2& x0, float2& x1, float2& x2, float2& x3,
                                           float c, float s) {
    float Ar = x0.x + x2.x, Ai = x0.y + x2.y;
    float Br = x0.x - x2.x, Bi = x0.y - x2.y;
    float Cr = x1.x + x3.x, Ci = x1.y + x3.y;
    float Dr = x1.x - x3.x, Di = x1.y - x3.y;
    float w2r = c * c - s * s, w2i = 2.f * c * s;
    float w3r = w2r * c - w2i * s, w3i = w2r * s + w2i * c;
    x0 = make_float2(Ar + Cr, Ai + Ci);
    x1 = cmul(make_float2(Br + Di, Bi - Dr), c, s);
    x2 = cmul(make_float2(Ar - Cr, Ai - Ci), w2r, w2i);
    x3 = cmul(make_float2(Br - Di, Bi + Dr), w3r, w3i);
}

// DIT radix-4 butterfly: twiddle-multiply inputs then combine.
__device__ __forceinline__ void bfly_dit_w(float2& x0, float2& x1, float2& x2, float2& x3,
                                           float c, float s) {
    float w2r = c * c - s * s, w2i = 2.f * c * s;
    float w3r = w2r * c - w2i * s, w3i = w2r * s + w2i * c;
    float2 a1 = cmul(x1, c, s);
    float2 a2 = cmul(x2, w2r, w2i);
    float2 a3 = cmul(x3, w3r, w3i);
    float Er = x0.x + a2.x, Ei = x0.y + a2.y;
    float Fr = x0.x - a2.x, Fi = x0.y - a2.y;
    float Gr = a1.x + a3.x, Gi = a1.y + a3.y;
    float Kr = a1.x - a3.x, Ki = a1.y - a3.y;
    x0 = make_float2(Er + Gr, Ei + Gi);
    x1 = make_float2(Fr - Ki, Fi + Kr);
    x2 = make_float2(Er - Gr, Ei - Gi);
    x3 = make_float2(Fr + Ki, Fi - Kr);
}

// twiddle-free DIF (t=0)
__device__ __forceinline__ void bfly_dif_1(float2* z) {
    float Ar = z[0].x + z[2].x, Ai = z[0].y + z[2].y;
    float Br = z[0].x - z[2].x, Bi = z[0].y - z[2].y;
    float Cr = z[1].x + z[3].x, Ci = z[1].y + z[3].y;
    float Dr = z[1].x - z[3].x, Di = z[1].y - z[3].y;
    z[0] = make_float2(Ar + Cr, Ai + Ci);
    z[1] = make_float2(Br + Di, Bi - Dr);
    z[2] = make_float2(Ar - Cr, Ai - Ci);
    z[3] = make_float2(Br - Di, Bi + Dr);
}

// twiddle-free DIT (t=0)
__device__ __forceinline__ void bfly_dit_1(float2* z) {
    float Er = z[0].x + z[2].x, Ei = z[0].y + z[2].y;
    float Fr = z[0].x - z[2].x, Fi = z[0].y - z[2].y;
    float Gr = z[1].x + z[3].x, Gi = z[1].y + z[3].y;
    float Kr = z[1].x - z[3].x, Ki = z[1].y - z[3].y;
    z[0] = make_float2(Er + Gr, Ei + Gi);
    z[1] = make_float2(Fr - Ki, Fi + Kr);
    z[2] = make_float2(Er - Gr, Ei - Gi);
    z[3] = make_float2(Fr + Ki, Fi - Kr);
}

// pointwise Y = X*H from Z[m], Z[N-m] of the packed z = x + i*h transform
__device__ __forceinline__ void pointwise_pair(float2& Zm, float2& Zr) {
    float Xr = 0.5f * (Zm.x + Zr.x), Xi = 0.5f * (Zm.y - Zr.y);
    float Hr = 0.5f * (Zm.y + Zr.y), Hi = 0.5f * (Zr.x - Zm.x);
    float Yr = Xr * Hr - Xi * Hi;
    float Yi = Xr * Hi + Xi * Hr;
    Zm = make_float2(Yr, Yi);
    Zr = make_float2(Yr, -Yi);
}

// Fused forward DIF pair: stage q=QA then q=QA/4, one LDS round-trip.
// Address algebra: i = base|jA*QA|jB*QB with disjoint bit fields for all QA
// used here, so lds index = swz(base) ^ swz(jA*QA+jB*QB) [constant].
template<int QA>
__device__ __forceinline__ void fwd_pair(float2* lds, int tid) {
    constexpr int QB = QA / 4;
    constexpr float C16v[4] = {1.0f, 0.92387953251128674f, 0.70710678118654752f, 0.38268343236508977f};
    constexpr float S16v[4] = {0.0f, 0.38268343236508977f, 0.70710678118654752f, 0.92387953251128674f};
    const int g = tid / QB;
    const int u = tid % QB;
    const int sb = swz(g * (4 * QA) + u);
    float2 r[4][4];
#pragma unroll
    for (int jA = 0; jA < 4; ++jA)
#pragma unroll
        for (int jB = 0; jB < 4; ++jB)
            r[jA][jB] = lds[sb ^ swz(jA * QA + jB * QB)];

    // Stage A twiddle for column jB is W^(u + jB*QB) = W^u * e^{-2pi*i*jB/16}
    const float angA = -6.283185307179586f / (float)(4 * QA);
    float snU, csU;
    __sincosf(angA * (float)u, &snU, &csU);
#pragma unroll
    for (int jB = 0; jB < 4; ++jB) {
        float c = csU * C16v[jB] + snU * S16v[jB];
        float s = snU * C16v[jB] - csU * S16v[jB];
        bfly_dif_w(r[0][jB], r[1][jB], r[2][jB], r[3][jB], c, s);
    }
    const float angB = -6.283185307179586f / (float)(4 * QB);
    float snB, csB;
    __sincosf(angB * (float)u, &snB, &csB);
#pragma unroll
    for (int jA = 0; jA < 4; ++jA)
        bfly_dif_w(r[jA][0], r[jA][1], r[jA][2], r[jA][3], csB, snB);

#pragma unroll
    for (int jA = 0; jA < 4; ++jA)
#pragma unroll
        for (int jB = 0; jB < 4; ++jB)
            lds[sb ^ swz(jA * QA + jB * QB)] = r[jA][jB];
}

// Fused inverse DIT pair: stage q=QA then q=4*QA, one LDS round-trip.
template<int QA>
__device__ __forceinline__ void inv_pair(float2* lds, int tid) {
    constexpr int QB = 4 * QA;
    constexpr float C16v[4] = {1.0f, 0.92387953251128674f, 0.70710678118654752f, 0.38268343236508977f};
    constexpr float S16v[4] = {0.0f, 0.38268343236508977f, 0.70710678118654752f, 0.92387953251128674f};
    const int G = tid / QA;
    const int u = tid % QA;
    const int sb = swz(G * (16 * QA) + u);
    float2 r[4][4];
#pragma unroll
    for (int jA = 0; jA < 4; ++jA)
#pragma unroll
        for (int jB = 0; jB < 4; ++jB)
            r[jA][jB] = lds[sb ^ swz(jA * QA + jB * QB)];

    const float angA = 6.283185307179586f / (float)(4 * QA);
    float snA, csA;
    __sincosf(angA * (float)u, &snA, &csA);
#pragma unroll
    for (int jB = 0; jB < 4; ++jB)
        bfly_dit_w(r[0][jB], r[1][jB], r[2][jB], r[3][jB], csA, snA);

    // Stage B twiddle for row jA is W^(u + jA*QA) = W^u * e^{+2pi*i*jA/16}
    const float angB = 6.283185307179586f / (float)(4 * QB);
    float snU, csU;
    __sincosf(angB * (float)u, &snU, &csU);
#pragma unroll
    for (int jA = 0; jA < 4; ++jA) {
        float c = csU * C16v[jA] - snU * S16v[jA];
        float s = snU * C16v[jA] + csU * S16v[jA];
        bfly_dit_w(r[jA][0], r[jA][1], r[jA][2], r[jA][3], c, s);
    }

#pragma unroll
    for (int jA = 0; jA < 4; ++jA)
#pragma unroll
        for (int jB = 0; jB < 4; ++jB)
            lds[sb ^ swz(jA * QA + jB * QB)] = r[jA][jB];
}

__global__ LB
void fftconv_kernel(const float* __restrict__ xin,
                    const float* __restrict__ hin,
                    float* __restrict__ out)
{
    __shared__ float2 lds[N_FFT];   // 128 KiB

    const int row = blockIdx.x;
    const int tid = threadIdx.x;
    const float* xr = xin + (size_t)row * L_LEN;
    const float* hr = hin + (size_t)row * L_LEN;

    // ---- load z = x + i*h, zero-pad to N ----
    // element index j = 4*tid + iter*4096 + k  (disjoint fields)
    const int s4t = swz(4 * tid);
#pragma unroll
    for (int iter = 0; iter < 2; ++iter) {
        float4 xv = ((const float4*)xr)[tid + iter * NB];
        float4 hv = ((const float4*)hr)[tid + iter * NB];
        lds[s4t ^ swz(iter * 4096 + 0)] = make_float2(xv.x, hv.x);
        lds[s4t ^ swz(iter * 4096 + 1)] = make_float2(xv.y, hv.y);
        lds[s4t ^ swz(iter * 4096 + 2)] = make_float2(xv.z, hv.z);
        lds[s4t ^ swz(iter * 4096 + 3)] = make_float2(xv.w, hv.w);
    }
    // zero-pad: j = 8192 + it*1024 + tid (disjoint fields)
    const int st = swz(tid);
#pragma unroll
    for (int it = 0; it < 8; ++it)
        lds[st ^ swz(8192 + it * 1024)] = make_float2(0.f, 0.f);
    __syncthreads();

    // ---- forward: fused radix-16 passes (q = 4096&1024, 256&64, 16&4) ----
    fwd_pair<4096>(lds, tid); __syncthreads();
    fwd_pair<256>(lds, tid);  __syncthreads();
    fwd_pair<16>(lds, tid);   __syncthreads();

    // ---- combo pass: fwd q=1 + Hermitian pointwise + inv q=1, in registers ----
    // Quad at positions 4a..4a+3 (a = rev6(b)) holds bins k*4096 + b.
    // Quad b pairs with quad 4096-b; entry k pairs with partner entry 3-k.
    // Note swz(k)=k for k<16, and swz(4a+k)=swz(4a)^k (disjoint fields).
#pragma unroll
    for (int iter = 0; iter < 2; ++iter) {
        const int p = tid + iter * NB;          // p in [0, 2048)
        if (p == 0) {
            // quad a=0 (b=0): bins {0,4096,8192,12288}; swz identity below 16
            float2 z[4];
#pragma unroll
            for (int k = 0; k < 4; ++k) z[k] = lds[k];
            bfly_dif_1(z);
            z[0] = make_float2(z[0].x * z[0].y, 0.f);   // bin 0
            z[2] = make_float2(z[2].x * z[2].y, 0.f);   // bin N/2
            pointwise_pair(z[1], z[3]);                 // 4096 <-> 12288
            bfly_dit_1(z);
#pragma unroll
            for (int k = 0; k < 4; ++k) lds[k] = z[k];
            // quad a=2 (b=2048): bins k*4096+2048; pairs (0,3),(1,2)
            float2 w[4];
#pragma unroll
            for (int k = 0; k < 4; ++k) w[k] = lds[8 + k];
            bfly_dif_1(w);
            pointwise_pair(w[0], w[3]);
            pointwise_pair(w[1], w[2]);
            bfly_dit_1(w);
#pragma unroll
            for (int k = 0; k < 4; ++k) lds[8 + k] = w[k];
        } else {
            const int sA = swz(4 * rev4_12(p));
            const int sB = swz(4 * rev4_12(4096 - p));
            float2 A[4], B[4];
#pragma unroll
            for (int k = 0; k < 4; ++k) A[k] = lds[sA ^ k];
#pragma unroll
            for (int k = 0; k < 4; ++k) B[k] = lds[sB ^ k];
            bfly_dif_1(A);
            bfly_dif_1(B);
            pointwise_pair(A[0], B[3]);
            pointwise_pair(A[1], B[2]);
            pointwise_pair(A[2], B[1]);
            pointwise_pair(A[3], B[0]);
            bfly_dit_1(A);
            bfly_dit_1(B);
#pragma unroll
            for (int k = 0; k < 4; ++k) lds[sA ^ k] = A[k];
#pragma unroll
            for (int k = 0; k < 4; ++k) lds[sB ^ k] = B[k];
        }
    }
    __syncthreads();

    // ---- inverse: fused radix-16 passes (q = 4&16, 64&256, 1024&4096) ----
    inv_pair<4>(lds, tid);    __syncthreads();
    inv_pair<64>(lds, tid);   __syncthreads();
    inv_pair<1024>(lds, tid); __syncthreads();

    // ---- store first L real parts, scaled by 1/N^2 (net torch-forward 1/n) ----
    const float scale = 1.0f / ((float)N_FFT * (float)N_FFT);   // 2^-28
    float* orow = out + (size_t)row * L_LEN;
#pragma unroll
    for (int iter = 0; iter < 2; ++iter) {
        float4 o;
        o.x = lds[s4t ^ swz(iter * 4096 + 0)].x * scale;
        o.y = lds[s4t ^ swz(iter * 4096 + 1)].x * scale;
        o.z = lds[s4t ^ swz(iter * 4096 + 2)].x * scale;
        o.w = lds[s4t ^ swz(iter * 4096 + 3)].x * scale;
        ((float4*)orow)[tid + iter * NB] = o;
    }
}

extern "C" void kernel_launch(void* const* d_in, const int* in_sizes, int n_in,
                              void* d_out, int out_size, void* d_ws, size_t ws_size,
                              hipStream_t stream) {
    const float* x = (const float*)d_in[0];
    const float* h = (const float*)d_in[1];
    float* out = (float*)d_out;
    const int rows = in_sizes[0] / L_LEN;   // 2048
    fftconv_kernel<<<dim3(rows), dim3(NB), 0, stream>>>(x, h, out);
}

// Round 7
// 126.618 us; speedup vs baseline: 1.7722x; 1.4833x over previous
//
#include <hip/hip_runtime.h>

#define L_LEN 8192
#define N_FFT 16384   // 2*L
#define NB    1024    // threads per block; each thread owns 16 points per pass

#define LB __launch_bounds__(NB)

// 2-wide float vector = one complex value (re, im). Arithmetic on this type
// emits gfx950 packed-fp32 ops (v_pk_add_f32 / v_pk_fma_f32) — 2x fp32 rate.
typedef float f2 __attribute__((ext_vector_type(2)));

__device__ __forceinline__ f2 mkf2(float a, float b) { f2 v; v.x = a; v.y = b; return v; }

// full complex multiply: (a.x w.x - a.y w.y, a.x w.y + a.y w.x) = 2 pk ops
__device__ __forceinline__ f2 cmul(f2 a, f2 w) {
    return mkf2(a.y, a.y) * mkf2(-w.y, w.x) + mkf2(a.x, a.x) * w;
}

// bijective LDS index swizzle: GF(2)-linear, so with disjoint bit fields
// swz(base+off) = swz(base) ^ swz(off) and swz(off) constant-folds.
__host__ __device__ constexpr int swz(int i) {
    return i ^ ((((i) >> 4) ^ ((i) >> 8) ^ ((i) >> 12)) & 15);
}

// reverse 6 base-4 digits (12-bit index)
__device__ __forceinline__ int rev4_12(int m) {
    int r = 0;
#pragma unroll
    for (int d = 0; d < 6; ++d) { r = (r << 2) | (m & 3); m >>= 2; }
    return r;
}

// DIF radix-4 butterfly, twiddles (w1,w2,w3) precomputed by caller.
__device__ __forceinline__ void bfly_dif(f2& x0, f2& x1, f2& x2, f2& x3,
                                         f2 w1, f2 w2, f2 w3) {
    f2 A = x0 + x2, B = x0 - x2, C = x1 + x3, D = x1 - x3;
    f2 iD = mkf2(-D.y, D.x);
    x0 = A + C;
    x1 = cmul(B - iD, w1);
    x2 = cmul(A - C, w2);
    x3 = cmul(B + iD, w3);
}

// DIT radix-4 butterfly: twiddle-multiply inputs then combine.
__device__ __forceinline__ void bfly_dit(f2& x0, f2& x1, f2& x2, f2& x3,
                                         f2 w1, f2 w2, f2 w3) {
    f2 a1 = cmul(x1, w1), a2 = cmul(x2, w2), a3 = cmul(x3, w3);
    f2 E = x0 + a2, F = x0 - a2, G = a1 + a3, K = a1 - a3;
    f2 iK = mkf2(-K.y, K.x);
    x0 = E + G; x1 = F + iK; x2 = E - G; x3 = F - iK;
}

// twiddle-free variants (t=0)
__device__ __forceinline__ void bfly_dif1(f2* z) {
    f2 A = z[0] + z[2], B = z[0] - z[2], C = z[1] + z[3], D = z[1] - z[3];
    f2 iD = mkf2(-D.y, D.x);
    z[0] = A + C; z[1] = B - iD; z[2] = A - C; z[3] = B + iD;
}
__device__ __forceinline__ void bfly_dit1(f2* z) {
    f2 E = z[0] + z[2], F = z[0] - z[2], G = z[1] + z[3], K = z[1] - z[3];
    f2 iK = mkf2(-K.y, K.x);
    z[0] = E + G; z[1] = F + iK; z[2] = E - G; z[3] = F - iK;
}

// pointwise Y = X*H from Z[m], Z[N-m] of the packed z = x + i*h transform
__device__ __forceinline__ void pointwise_pair(f2& Zm, f2& Zr) {
    f2 half = mkf2(0.5f, 0.5f);
    f2 X = half * (Zm + mkf2(Zr.x, -Zr.y));
    f2 H = half * (mkf2(Zm.y, -Zm.x) + mkf2(Zr.y, Zr.x));
    f2 Y = cmul(X, H);
    Zm = Y;
    Zr = mkf2(Y.x, -Y.y);
}

// cos/sin of 2*pi*j/16, j=0..3
#define CT0 1.0f
#define CT1 0.92387953251128674f
#define CT2 0.70710678118654752f
#define CT3 0.38268343236508977f
#define ST1 0.38268343236508977f
#define ST2 0.70710678118654752f
#define ST3 0.92387953251128674f

// Fused forward DIF pair: stage q=QA then q=QA/4, one LDS round-trip.
template<int QA>
__device__ __forceinline__ void fwd_pair(f2* lds, int tid) {
    constexpr int QB = QA / 4;
    const int g = tid / QB;
    const int u = tid % QB;
    const int sb = swz(g * (4 * QA) + u);
    f2 r[4][4];
#pragma unroll
    for (int jA = 0; jA < 4; ++jA)
#pragma unroll
        for (int jB = 0; jB < 4; ++jB)
            r[jA][jB] = lds[sb ^ swz(jA * QA + jB * QB)];

    // Stage A: twiddle for column jB is W^(u + jB*QB) = W^u * e^{-2pi*i*jB/16}
    {
        const float angA = -6.283185307179586f / (float)(4 * QA);
        float sn, cs;
        __sincosf(angA * (float)u, &sn, &cs);
        f2 u1 = mkf2(cs, sn);
        // fwd ladder constants e^{-2pi*i*jB/16} = (C, -S)
        const f2 lad[4] = {mkf2(CT0, 0.f), mkf2(CT1, -ST1), mkf2(CT2, -ST2), mkf2(CT3, -ST3)};
#pragma unroll
        for (int jB = 0; jB < 4; ++jB) {
            f2 w1 = (jB == 0) ? u1 : cmul(u1, lad[jB]);
            f2 w2 = cmul(w1, w1);
            f2 w3 = cmul(w2, w1);
            bfly_dif(r[0][jB], r[1][jB], r[2][jB], r[3][jB], w1, w2, w3);
        }
    }
    // Stage B: same twiddle V^u for all rows
    {
        const float angB = -6.283185307179586f / (float)(4 * QB);
        float sn, cs;
        __sincosf(angB * (float)u, &sn, &cs);
        f2 v1 = mkf2(cs, sn);
        f2 v2 = cmul(v1, v1);
        f2 v3 = cmul(v2, v1);
#pragma unroll
        for (int jA = 0; jA < 4; ++jA)
            bfly_dif(r[jA][0], r[jA][1], r[jA][2], r[jA][3], v1, v2, v3);
    }

#pragma unroll
    for (int jA = 0; jA < 4; ++jA)
#pragma unroll
        for (int jB = 0; jB < 4; ++jB)
            lds[sb ^ swz(jA * QA + jB * QB)] = r[jA][jB];
}

// Fused inverse DIT pair: stage q=QA then q=4*QA, one LDS round-trip.
template<int QA>
__device__ __forceinline__ void inv_pair(f2* lds, int tid) {
    constexpr int QB = 4 * QA;
    const int G = tid / QA;
    const int u = tid % QA;
    const int sb = swz(G * (16 * QA) + u);
    f2 r[4][4];
#pragma unroll
    for (int jA = 0; jA < 4; ++jA)
#pragma unroll
        for (int jB = 0; jB < 4; ++jB)
            r[jA][jB] = lds[sb ^ swz(jA * QA + jB * QB)];

    // Stage A: same twiddle W^u for all columns
    {
        const float angA = 6.283185307179586f / (float)(4 * QA);
        float sn, cs;
        __sincosf(angA * (float)u, &sn, &cs);
        f2 a1 = mkf2(cs, sn);
        f2 a2 = cmul(a1, a1);
        f2 a3 = cmul(a2, a1);
#pragma unroll
        for (int jB = 0; jB < 4; ++jB)
            bfly_dit(r[0][jB], r[1][jB], r[2][jB], r[3][jB], a1, a2, a3);
    }
    // Stage B: twiddle for row jA is V^(u + jA*QA) = V^u * e^{+2pi*i*jA/16}
    {
        const float angB = 6.283185307179586f / (float)(4 * QB);
        float sn, cs;
        __sincosf(angB * (float)u, &sn, &cs);
        f2 b1 = mkf2(cs, sn);
        // inverse ladder constants e^{+2pi*i*jA/16} = (C, +S)
        const f2 lad[4] = {mkf2(CT0, 0.f), mkf2(CT1, ST1), mkf2(CT2, ST2), mkf2(CT3, ST3)};
#pragma unroll
        for (int jA = 0; jA < 4; ++jA) {
            f2 w1 = (jA == 0) ? b1 : cmul(b1, lad[jA]);
            f2 w2 = cmul(w1, w1);
            f2 w3 = cmul(w2, w1);
            bfly_dit(r[jA][0], r[jA][1], r[jA][2], r[jA][3], w1, w2, w3);
        }
    }

#pragma unroll
    for (int jA = 0; jA < 4; ++jA)
#pragma unroll
        for (int jB = 0; jB < 4; ++jB)
            lds[sb ^ swz(jA * QA + jB * QB)] = r[jA][jB];
}

__global__ LB
void fftconv_kernel(const float* __restrict__ xin,
                    const float* __restrict__ hin,
                    float* __restrict__ out)
{
    __shared__ f2 lds[N_FFT];   // 128 KiB

    const int row = blockIdx.x;
    const int tid = threadIdx.x;
    const float* xr = xin + (size_t)row * L_LEN;
    const float* hr = hin + (size_t)row * L_LEN;

    // ---- load z = x + i*h, zero-pad to N ----
    // element index j = 4*tid + iter*4096 + k  (disjoint fields)
    const int s4t = swz(4 * tid);
#pragma unroll
    for (int iter = 0; iter < 2; ++iter) {
        float4 xv = ((const float4*)xr)[tid + iter * NB];
        float4 hv = ((const float4*)hr)[tid + iter * NB];
        lds[s4t ^ swz(iter * 4096 + 0)] = mkf2(xv.x, hv.x);
        lds[s4t ^ swz(iter * 4096 + 1)] = mkf2(xv.y, hv.y);
        lds[s4t ^ swz(iter * 4096 + 2)] = mkf2(xv.z, hv.z);
        lds[s4t ^ swz(iter * 4096 + 3)] = mkf2(xv.w, hv.w);
    }
    // zero-pad: j = 8192 + it*1024 + tid (disjoint fields)
    const int st = swz(tid);
#pragma unroll
    for (int it = 0; it < 8; ++it)
        lds[st ^ swz(8192 + it * 1024)] = mkf2(0.f, 0.f);
    __syncthreads();

    // ---- forward: fused radix-16 passes (q = 4096&1024, 256&64, 16&4) ----
    fwd_pair<4096>(lds, tid); __syncthreads();
    fwd_pair<256>(lds, tid);  __syncthreads();
    fwd_pair<16>(lds, tid);   __syncthreads();

    // ---- combo pass: fwd q=1 + Hermitian pointwise + inv q=1, in registers ----
    // Quad at positions 4a..4a+3 (a = rev6(b)) holds bins k*4096 + b.
    // Quad b pairs with quad 4096-b; entry k pairs with partner entry 3-k.
    // swz(k)=k for k<16, and swz(4a+k)=swz(4a)^k (disjoint fields).
#pragma unroll
    for (int iter = 0; iter < 2; ++iter) {
        const int p = tid + iter * NB;          // p in [0, 2048)
        if (p == 0) {
            // quad a=0 (b=0): bins {0,4096,8192,12288}
            f2 z[4];
#pragma unroll
            for (int k = 0; k < 4; ++k) z[k] = lds[k];
            bfly_dif1(z);
            z[0] = mkf2(z[0].x * z[0].y, 0.f);   // bin 0
            z[2] = mkf2(z[2].x * z[2].y, 0.f);   // bin N/2
            pointwise_pair(z[1], z[3]);          // 4096 <-> 12288
            bfly_dit1(z);
#pragma unroll
            for (int k = 0; k < 4; ++k) lds[k] = z[k];
            // quad a=2 (b=2048): bins k*4096+2048; pairs (0,3),(1,2)
            f2 w[4];
#pragma unroll
            for (int k = 0; k < 4; ++k) w[k] = lds[8 + k];
            bfly_dif1(w);
            pointwise_pair(w[0], w[3]);
            pointwise_pair(w[1], w[2]);
            bfly_dit1(w);
#pragma unroll
            for (int k = 0; k < 4; ++k) lds[8 + k] = w[k];
        } else {
            const int sA = swz(4 * rev4_12(p));
            const int sB = swz(4 * rev4_12(4096 - p));
            f2 A[4], B[4];
#pragma unroll
            for (int k = 0; k < 4; ++k) A[k] = lds[sA ^ k];
#pragma unroll
            for (int k = 0; k < 4; ++k) B[k] = lds[sB ^ k];
            bfly_dif1(A);
            bfly_dif1(B);
            pointwise_pair(A[0], B[3]);
            pointwise_pair(A[1], B[2]);
            pointwise_pair(A[2], B[1]);
            pointwise_pair(A[3], B[0]);
            bfly_dit1(A);
            bfly_dit1(B);
#pragma unroll
            for (int k = 0; k < 4; ++k) lds[sA ^ k] = A[k];
#pragma unroll
            for (int k = 0; k < 4; ++k) lds[sB ^ k] = B[k];
        }
    }
    __syncthreads();

    // ---- inverse: fused radix-16 passes (q = 4&16, 64&256, 1024&4096) ----
    inv_pair<4>(lds, tid);    __syncthreads();
    inv_pair<64>(lds, tid);   __syncthreads();
    inv_pair<1024>(lds, tid); __syncthreads();

    // ---- store first L real parts, scaled by 1/N^2 (net torch-forward 1/n) ----
    const float scale = 1.0f / ((float)N_FFT * (float)N_FFT);   // 2^-28
    float* orow = out + (size_t)row * L_LEN;
#pragma unroll
    for (int iter = 0; iter < 2; ++iter) {
        float4 o;
        o.x = lds[s4t ^ swz(iter * 4096 + 0)].x * scale;
        o.y = lds[s4t ^ swz(iter * 4096 + 1)].x * scale;
        o.z = lds[s4t ^ swz(iter * 4096 + 2)].x * scale;
        o.w = lds[s4t ^ swz(iter * 4096 + 3)].x * scale;
        ((float4*)orow)[tid + iter * NB] = o;
    }
}

extern "C" void kernel_launch(void* const* d_in, const int* in_sizes, int n_in,
                              void* d_out, int out_size, void* d_ws, size_t ws_size,
                              hipStream_t stream) {
    const float* x = (const float*)d_in[0];
    const float* h = (const float*)d_in[1];
    float* out = (float*)d_out;
    const int rows = in_sizes[0] / L_LEN;   // 2048
    fftconv_kernel<<<dim3(rows), dim3(NB), 0, stream>>>(x, h, out);
}

// Round 8
// 113.054 us; speedup vs baseline: 1.9848x; 1.1200x over previous
//
#include <hip/hip_runtime.h>

#define L_LEN 8192
#define N_FFT 16384   // 2*L
#define NB    1024    // threads per block; each thread owns 16 points per pass

#define LB __launch_bounds__(NB)

// 2-wide float vector = one complex value (re, im). Arithmetic on this type
// emits gfx950 packed-fp32 ops (v_pk_add_f32 / v_pk_fma_f32) — 2x fp32 rate.
typedef float f2 __attribute__((ext_vector_type(2)));

__device__ __forceinline__ f2 mkf2(float a, float b) { f2 v; v.x = a; v.y = b; return v; }

// full complex multiply: 2 pk ops
__device__ __forceinline__ f2 cmul(f2 a, f2 w) {
    return mkf2(a.y, a.y) * mkf2(-w.y, w.x) + mkf2(a.x, a.x) * w;
}

// bijective LDS index swizzle: GF(2)-linear, so with disjoint bit fields
// swz(base+off) = swz(base) ^ swz(off) and swz(off) constant-folds.
__host__ __device__ constexpr int swz(int i) {
    return i ^ ((((i) >> 4) ^ ((i) >> 8) ^ ((i) >> 12)) & 15);
}

// reverse 6 base-4 digits (12-bit index)
__device__ __forceinline__ int rev4_12(int m) {
    int r = 0;
#pragma unroll
    for (int d = 0; d < 6; ++d) { r = (r << 2) | (m & 3); m >>= 2; }
    return r;
}

// DIF radix-4 butterfly, twiddles (w1,w2,w3) precomputed by caller.
__device__ __forceinline__ void bfly_dif(f2& x0, f2& x1, f2& x2, f2& x3,
                                         f2 w1, f2 w2, f2 w3) {
    f2 A = x0 + x2, B = x0 - x2, C = x1 + x3, D = x1 - x3;
    f2 iD = mkf2(-D.y, D.x);
    x0 = A + C;
    x1 = cmul(B - iD, w1);
    x2 = cmul(A - C, w2);
    x3 = cmul(B + iD, w3);
}

// DIT radix-4 butterfly: twiddle-multiply inputs then combine.
__device__ __forceinline__ void bfly_dit(f2& x0, f2& x1, f2& x2, f2& x3,
                                         f2 w1, f2 w2, f2 w3) {
    f2 a1 = cmul(x1, w1), a2 = cmul(x2, w2), a3 = cmul(x3, w3);
    f2 E = x0 + a2, F = x0 - a2, G = a1 + a3, K = a1 - a3;
    f2 iK = mkf2(-K.y, K.x);
    x0 = E + G; x1 = F + iK; x2 = E - G; x3 = F - iK;
}

// twiddle-free variants (t=0)
__device__ __forceinline__ void bfly_dif1(f2* z) {
    f2 A = z[0] + z[2], B = z[0] - z[2], C = z[1] + z[3], D = z[1] - z[3];
    f2 iD = mkf2(-D.y, D.x);
    z[0] = A + C; z[1] = B - iD; z[2] = A - C; z[3] = B + iD;
}
__device__ __forceinline__ void bfly_dit1(f2* z) {
    f2 E = z[0] + z[2], F = z[0] - z[2], G = z[1] + z[3], K = z[1] - z[3];
    f2 iK = mkf2(-K.y, K.x);
    z[0] = E + G; z[1] = F + iK; z[2] = E - G; z[3] = F - iK;
}

// pointwise Y = X*H from Z[m], Z[N-m] of the packed z = x + i*h transform
__device__ __forceinline__ void pointwise_pair(f2& Zm, f2& Zr) {
    f2 half = mkf2(0.5f, 0.5f);
    f2 X = half * (Zm + mkf2(Zr.x, -Zr.y));
    f2 H = half * (mkf2(Zm.y, -Zm.x) + mkf2(Zr.y, Zr.x));
    f2 Y = cmul(X, H);
    Zm = Y;
    Zr = mkf2(Y.x, -Y.y);
}

// cos/sin of 2*pi*j/16, j=0..3
#define CT0 1.0f
#define CT1 0.92387953251128674f
#define CT2 0.70710678118654752f
#define CT3 0.38268343236508977f
#define ST1 0.38268343236508977f
#define ST2 0.70710678118654752f
#define ST3 0.92387953251128674f

// First forward double-stage (q=4096 then q=1024), fused with global load.
// Upper half of the zero-padded input is 0: x2=x3=0 in the q=4096 butterfly.
__device__ __forceinline__ void fwd_first(f2* lds, int tid,
                                          const float* __restrict__ xr,
                                          const float* __restrict__ hr) {
    f2 r[4][4];
    const float angA = -6.283185307179586f / 16384.f;
    float snA, csA;
    __sincosf(angA * (float)tid, &snA, &csA);
    f2 u1 = mkf2(csA, snA);
    const f2 lad[4] = {mkf2(CT0, 0.f), mkf2(CT1, -ST1), mkf2(CT2, -ST2), mkf2(CT3, -ST3)};
#pragma unroll
    for (int jB = 0; jB < 4; ++jB) {
        const int t = tid + jB * 1024;
        f2 z0 = mkf2(xr[t], hr[t]);
        f2 z1 = mkf2(xr[t + 4096], hr[t + 4096]);
        f2 w1 = (jB == 0) ? u1 : cmul(u1, lad[jB]);
        f2 w2 = cmul(w1, w1);
        f2 w3 = cmul(w2, w1);
        f2 iz1 = mkf2(-z1.y, z1.x);
        r[0][jB] = z0 + z1;                 // A + C
        r[1][jB] = cmul(z0 - iz1, w1);      // (B - iD) W
        r[2][jB] = cmul(z0 - z1, w2);       // (A - C) W^2
        r[3][jB] = cmul(z0 + iz1, w3);      // (B + iD) W^3
    }
    // stage B (q=1024): same twiddle V^tid for all rows, V = e^{-2pi*i/4096}
    const float angB = -6.283185307179586f / 4096.f;
    float sn, cs;
    __sincosf(angB * (float)tid, &sn, &cs);
    f2 v1 = mkf2(cs, sn);
    f2 v2 = cmul(v1, v1);
    f2 v3 = cmul(v2, v1);
#pragma unroll
    for (int jA = 0; jA < 4; ++jA)
        bfly_dif(r[jA][0], r[jA][1], r[jA][2], r[jA][3], v1, v2, v3);

    const int sb = swz(tid);
#pragma unroll
    for (int jA = 0; jA < 4; ++jA)
#pragma unroll
        for (int jB = 0; jB < 4; ++jB)
            lds[sb ^ swz(jA * 4096 + jB * 1024)] = r[jA][jB];
}

// Last inverse double-stage (q=1024 then q=4096), fused with global store.
// Only outputs n < 8192 (jB<2) are needed, and only their real parts.
__device__ __forceinline__ void inv_last(const f2* lds, int tid,
                                         float* __restrict__ orow) {
    const int sb = swz(tid);
    f2 r[4][4];
#pragma unroll
    for (int jA = 0; jA < 4; ++jA)
#pragma unroll
        for (int jB = 0; jB < 4; ++jB)
            r[jA][jB] = lds[sb ^ swz(jA * 1024 + jB * 4096)];

    // stage A (q=1024): same twiddle for all columns, e^{+2pi*i*tid/4096}
    {
        const float angA = 6.283185307179586f / 4096.f;
        float sn, cs;
        __sincosf(angA * (float)tid, &sn, &cs);
        f2 a1 = mkf2(cs, sn);
        f2 a2 = cmul(a1, a1);
        f2 a3 = cmul(a2, a1);
#pragma unroll
        for (int jB = 0; jB < 4; ++jB)
            bfly_dit(r[0][jB], r[1][jB], r[2][jB], r[3][jB], a1, a2, a3);
    }
    // stage B (q=4096): twiddle w1 = e^{+2pi*i*(tid + jA*1024)/16384};
    // emit real parts of y0 (n = t) and y1 (n = t + 4096) only.
    const float scale = 1.0f / ((float)N_FFT * (float)N_FFT);   // 2^-28
    const float angB = 6.283185307179586f / 16384.f;
    float sn, cs;
    __sincosf(angB * (float)tid, &sn, &cs);
    f2 b1 = mkf2(cs, sn);
    const f2 lad[4] = {mkf2(CT0, 0.f), mkf2(CT1, ST1), mkf2(CT2, ST2), mkf2(CT3, ST3)};
#pragma unroll
    for (int jA = 0; jA < 4; ++jA) {
        f2 w1 = (jA == 0) ? b1 : cmul(b1, lad[jA]);
        f2 w2 = cmul(w1, w1);
        f2 w3 = cmul(w2, w1);
        f2 x0 = r[jA][0];
        f2 a1 = cmul(r[jA][1], w1);
        f2 a2 = cmul(r[jA][2], w2);
        f2 a3 = cmul(r[jA][3], w3);
        // y0 = (x0+a2) + (a1+a3);  y1 = (x0-a2) + i(a1-a3)
        float y0 = x0.x + a2.x + a1.x + a3.x;
        float y1 = x0.x - a2.x - a1.y + a3.y;
        orow[tid + jA * 1024]        = y0 * scale;
        orow[tid + jA * 1024 + 4096] = y1 * scale;
    }
}

// Fused forward DIF pair: stage q=QA then q=QA/4, one LDS round-trip.
template<int QA>
__device__ __forceinline__ void fwd_pair(f2* lds, int tid) {
    constexpr int QB = QA / 4;
    const int g = tid / QB;
    const int u = tid % QB;
    const int sb = swz(g * (4 * QA) + u);
    f2 r[4][4];
#pragma unroll
    for (int jA = 0; jA < 4; ++jA)
#pragma unroll
        for (int jB = 0; jB < 4; ++jB)
            r[jA][jB] = lds[sb ^ swz(jA * QA + jB * QB)];

    {
        const float angA = -6.283185307179586f / (float)(4 * QA);
        float sn, cs;
        __sincosf(angA * (float)u, &sn, &cs);
        f2 u1 = mkf2(cs, sn);
        const f2 lad[4] = {mkf2(CT0, 0.f), mkf2(CT1, -ST1), mkf2(CT2, -ST2), mkf2(CT3, -ST3)};
#pragma unroll
        for (int jB = 0; jB < 4; ++jB) {
            f2 w1 = (jB == 0) ? u1 : cmul(u1, lad[jB]);
            f2 w2 = cmul(w1, w1);
            f2 w3 = cmul(w2, w1);
            bfly_dif(r[0][jB], r[1][jB], r[2][jB], r[3][jB], w1, w2, w3);
        }
    }
    {
        const float angB = -6.283185307179586f / (float)(4 * QB);
        float sn, cs;
        __sincosf(angB * (float)u, &sn, &cs);
        f2 v1 = mkf2(cs, sn);
        f2 v2 = cmul(v1, v1);
        f2 v3 = cmul(v2, v1);
#pragma unroll
        for (int jA = 0; jA < 4; ++jA)
            bfly_dif(r[jA][0], r[jA][1], r[jA][2], r[jA][3], v1, v2, v3);
    }

#pragma unroll
    for (int jA = 0; jA < 4; ++jA)
#pragma unroll
        for (int jB = 0; jB < 4; ++jB)
            lds[sb ^ swz(jA * QA + jB * QB)] = r[jA][jB];
}

// Fused inverse DIT pair: stage q=QA then q=4*QA, one LDS round-trip.
template<int QA>
__device__ __forceinline__ void inv_pair(f2* lds, int tid) {
    constexpr int QB = 4 * QA;
    const int G = tid / QA;
    const int u = tid % QA;
    const int sb = swz(G * (16 * QA) + u);
    f2 r[4][4];
#pragma unroll
    for (int jA = 0; jA < 4; ++jA)
#pragma unroll
        for (int jB = 0; jB < 4; ++jB)
            r[jA][jB] = lds[sb ^ swz(jA * QA + jB * QB)];

    {
        const float angA = 6.283185307179586f / (float)(4 * QA);
        float sn, cs;
        __sincosf(angA * (float)u, &sn, &cs);
        f2 a1 = mkf2(cs, sn);
        f2 a2 = cmul(a1, a1);
        f2 a3 = cmul(a2, a1);
#pragma unroll
        for (int jB = 0; jB < 4; ++jB)
            bfly_dit(r[0][jB], r[1][jB], r[2][jB], r[3][jB], a1, a2, a3);
    }
    {
        const float angB = 6.283185307179586f / (float)(4 * QB);
        float sn, cs;
        __sincosf(angB * (float)u, &sn, &cs);
        f2 b1 = mkf2(cs, sn);
        const f2 lad[4] = {mkf2(CT0, 0.f), mkf2(CT1, ST1), mkf2(CT2, ST2), mkf2(CT3, ST3)};
#pragma unroll
        for (int jA = 0; jA < 4; ++jA) {
            f2 w1 = (jA == 0) ? b1 : cmul(b1, lad[jA]);
            f2 w2 = cmul(w1, w1);
            f2 w3 = cmul(w2, w1);
            bfly_dit(r[jA][0], r[jA][1], r[jA][2], r[jA][3], w1, w2, w3);
        }
    }

#pragma unroll
    for (int jA = 0; jA < 4; ++jA)
#pragma unroll
        for (int jB = 0; jB < 4; ++jB)
            lds[sb ^ swz(jA * QA + jB * QB)] = r[jA][jB];
}

__global__ LB
void fftconv_kernel(const float* __restrict__ xin,
                    const float* __restrict__ hin,
                    float* __restrict__ out)
{
    __shared__ f2 lds[N_FFT];   // 128 KiB

    const int row = blockIdx.x;
    const int tid = threadIdx.x;
    const float* xr = xin + (size_t)row * L_LEN;
    const float* hr = hin + (size_t)row * L_LEN;

    // ---- forward: fused global-load + q=4096&1024; then 256&64, 16&4 ----
    fwd_first(lds, tid, xr, hr); __syncthreads();
    fwd_pair<256>(lds, tid);     __syncthreads();
    fwd_pair<16>(lds, tid);      __syncthreads();

    // ---- combo pass: fwd q=1 + Hermitian pointwise + inv q=1, in registers ----
    // Quad at positions 4a..4a+3 (a = rev6(b)) holds bins k*4096 + b.
    // Quad b pairs with quad 4096-b; entry k pairs with partner entry 3-k.
    // swz(k)=k for k<16, and swz(4a+k)=swz(4a)^k (disjoint fields).
#pragma unroll
    for (int iter = 0; iter < 2; ++iter) {
        const int p = tid + iter * NB;          // p in [0, 2048)
        if (p == 0) {
            // quad a=0 (b=0): bins {0,4096,8192,12288}
            f2 z[4];
#pragma unroll
            for (int k = 0; k < 4; ++k) z[k] = lds[k];
            bfly_dif1(z);
            z[0] = mkf2(z[0].x * z[0].y, 0.f);   // bin 0
            z[2] = mkf2(z[2].x * z[2].y, 0.f);   // bin N/2
            pointwise_pair(z[1], z[3]);          // 4096 <-> 12288
            bfly_dit1(z);
#pragma unroll
            for (int k = 0; k < 4; ++k) lds[k] = z[k];
            // quad a=2 (b=2048): bins k*4096+2048; pairs (0,3),(1,2)
            f2 w[4];
#pragma unroll
            for (int k = 0; k < 4; ++k) w[k] = lds[8 + k];
            bfly_dif1(w);
            pointwise_pair(w[0], w[3]);
            pointwise_pair(w[1], w[2]);
            bfly_dit1(w);
#pragma unroll
            for (int k = 0; k < 4; ++k) lds[8 + k] = w[k];
        } else {
            const int sA = swz(4 * rev4_12(p));
            const int sB = swz(4 * rev4_12(4096 - p));
            f2 A[4], B[4];
#pragma unroll
            for (int k = 0; k < 4; ++k) A[k] = lds[sA ^ k];
#pragma unroll
            for (int k = 0; k < 4; ++k) B[k] = lds[sB ^ k];
            bfly_dif1(A);
            bfly_dif1(B);
            pointwise_pair(A[0], B[3]);
            pointwise_pair(A[1], B[2]);
            pointwise_pair(A[2], B[1]);
            pointwise_pair(A[3], B[0]);
            bfly_dit1(A);
            bfly_dit1(B);
#pragma unroll
            for (int k = 0; k < 4; ++k) lds[sA ^ k] = A[k];
#pragma unroll
            for (int k = 0; k < 4; ++k) lds[sB ^ k] = B[k];
        }
    }
    __syncthreads();

    // ---- inverse: q=4&16, 64&256; then fused q=1024&4096 + store ----
    inv_pair<4>(lds, tid);  __syncthreads();
    inv_pair<64>(lds, tid); __syncthreads();
    inv_last(lds, tid, out + (size_t)row * L_LEN);
}

extern "C" void kernel_launch(void* const* d_in, const int* in_sizes, int n_in,
                              void* d_out, int out_size, void* d_ws, size_t ws_size,
                              hipStream_t stream) {
    const float* x = (const float*)d_in[0];
    const float* h = (const float*)d_in[1];
    float* out = (float*)d_out;
    const int rows = in_sizes[0] / L_LEN;   // 2048
    fftconv_kernel<<<dim3(rows), dim3(NB), 0, stream>>>(x, h, out);
}